// Round 5
// baseline (220.207 us; speedup 1.0000x reference)
//
#include <hip/hip_runtime.h>
#include <math.h>

#define NSTATES 21
#define NPULSES 128
#define BATCH   8192
#define CHUNK   4      // pulses staged per store burst
#define WPB     8      // waves per block
#define EPW     2      // batch elems per wave (lanes 0-20 and 32-52)
#define EPB     (WPB * EPW)   // 16 batch elems per block
#define RECF    (NSTATES * 10)  // 210 floats per (batch,pulse) record

typedef float v4f __attribute__((ext_vector_type(4)));

// R5 redesign: perfectly balanced, barrier-free, burst-structured.
//  - 512 blocks x 512 threads: 8192 = 512*16 exactly -> 2 blocks/CU, no tail,
//    4 waves/SIMD (was 2.67 with 683 blocks).
//  - 2 batch elems per wave at lanes 0-20 / 32-52 (s = lane&31, g = lane>>5).
//    Shuffle shift stays wave-local; s==0 / s==20 zero-fill masks group edges.
//  - NO block barriers anywhere: each wave owns a private LDS region, stages
//    its own records, copies its own output slice. Waves free-run and
//    de-phase, overlapping compute with store-queue drain across the CU.
//  - CHUNK=4 pulses staged per burst -> long back-to-back dwordx4 store
//    sequences (the pattern the 6.8 TB/s fill kernel uses).
__global__ __launch_bounds__(512) void epg_mt_kernel(
    const float* __restrict__ fa_arr,
    const float* __restrict__ ph_arr,
    const float* __restrict__ T1f, const float* __restrict__ T2f,
    const float* __restrict__ T1b, const float* __restrict__ T2b,
    const float* __restrict__ kfp, const float* __restrict__ kbp,
    const float* __restrict__ B0p, const float* __restrict__ B1p,
    const float* __restrict__ wfp, const float* __restrict__ wbp,
    const int*   __restrict__ TRp,
    float* __restrict__ out)
{
    // per-wave private staging: WPB x CHUNK x (2 records of 210 floats)
    __shared__ __attribute__((aligned(16))) float lds[WPB][CHUNK * EPW * RECF];

    const int tid  = threadIdx.x;
    const int wv   = tid >> 6;          // wave 0..7
    const int lane = tid & 63;
    const int g    = lane >> 5;         // elem-in-wave 0..1
    const int s    = lane & 31;         // state 0..31 (21..31 idle)
    const bool valid = (s < NSTATES);
    const int b    = blockIdx.x * EPB + wv * EPW + g;   // always < 8192

    float* ldsw = lds[wv];
    // Wave-local zero init (covers the always-zero output fields 5..8,
    // which are never rewritten). No barrier needed: wave-private region,
    // DS ops in-order per wave + compiler lgkmcnt on first dependent read.
    for (int i = lane; i < CHUNK * EPW * RECF; i += 64)
        ldsw[i] = 0.f;

    const float tr  = (float)TRp[0];
    const float dt  = tr * 0.001f;
    const float E1f = expf(-tr / T1f[b]);
    const float E2f = expf(-tr / T2f[b]);
    const float E1b = expf(-tr / T1b[b]);
    const float kfdt = kfp[b] * dt;
    const float kbdt = kbp[b] * dt;
    const float phi  = 6.28318530717958647692f * B0p[b] * dt;
    const float b0c  = cosf(phi), b0s = sinf(phi);
    const float wfv  = wfp[b], wbv = wbp[b];
    const float add0f = (s == 0) ? (1.0f - E1f) * wfv : 0.0f;
    const float add0b = (s == 0) ? (1.0f - E1b) * wbv : 0.0f;
    const float b1   = B1p[b];

    float Fpr = 0.f, Fpi = 0.f, Fmr = 0.f, Fmi = 0.f;
    float Zf = (s == 0) ? wfv : 0.f;
    float Zb = (s == 0) ? wbv : 0.f;

    const size_t pstride = (size_t)BATCH * RECF;   // floats per pulse slab
    float* outw = out + ((size_t)blockIdx.x * EPB + wv * EPW) * RECF;

    auto step = [&](float fa, float ph) {
        // relax + exchange
        Fpr *= E2f; Fpi *= E2f; Fmr *= E2f; Fmi *= E2f;
        const float dZf = kbdt * Zb - kfdt * Zf;
        const float dZb = kfdt * Zf - kbdt * Zb;
        const float nZf1 = fmaf(Zf, E1f, add0f) + dZf;
        const float nZb1 = fmaf(Zb, E1b, add0b) + dZb;
        Zf = nZf1; Zb = nZb1;
        {   // B0 precession (free pool; bound-pool F identically zero)
            const float r  = Fpr * b0c - Fpi * b0s;
            const float i_ = Fpr * b0s + Fpi * b0c;
            const float r2 = Fmr * b0c + Fmi * b0s;
            const float i2 = Fmi * b0c - Fmr * b0s;
            Fpr = r; Fpi = i_; Fmr = r2; Fmi = i2;
        }
        // RF pulse (free pool only)
        const float half = 0.5f * fa * b1;
        const float ca = __cosf(half), sa = __sinf(half);
        const float cph = __cosf(ph), sph = __sinf(ph);
        const float ca2 = ca * ca, sa2 = sa * sa, casa = ca * sa;
        const float cd  = ca2 - sa2;
        const float e2c = cph * cph - sph * sph;
        const float e2s = 2.f * cph * sph;
        const float t1r = Fmr * e2c + Fmi * e2s;     // conj(Fmf)*eib^2
        const float t1i = Fmr * e2s - Fmi * e2c;
        const float t2r = Fpr * e2c - Fpi * e2s;     // conj(Fpf)*conj(eib^2)
        const float t2i = -(Fpr * e2s) - Fpi * e2c;
        const float zc = Zf * cph, zs = Zf * sph;    // Zf * eib
        const float nFpr = ca2 * Fpr + sa2 * t1r - casa * zs;
        const float nFpi = ca2 * Fpi + sa2 * t1i + casa * zc;
        const float nFmr = sa2 * t2r + ca2 * Fmr - casa * zs;
        const float nFmi = sa2 * t2i + ca2 * Fmi - casa * zc;
        const float nZf = casa * ((Fpi * cph - Fpr * sph) - (Fmi * cph + Fmr * sph)) + cd * Zf;
        Fpr = nFpr; Fpi = nFpi; Fmr = nFmr; Fmi = nFmi; Zf = nZf;
        // EPG shift (lane +/-1; s==0 / s==20 zero-fill masks group edges)
        const float sFpr = __shfl_up(Fpr, 1);
        const float sFpi = __shfl_up(Fpi, 1);
        const float sZf  = __shfl_up(Zf, 1);
        const float sZb  = __shfl_up(Zb, 1);
        const float sFmr = __shfl_down(Fmr, 1);
        const float sFmi = __shfl_down(Fmi, 1);
        const bool s0 = (s == 0), sE = (s == NSTATES - 1);
        Fpr = s0 ? 0.f : sFpr;
        Fpi = s0 ? 0.f : sFpi;
        Zf  = s0 ? 0.f : sZf;
        Zb  = s0 ? 0.f : sZb;
        Fmr = sE ? 0.f : sFmr;
        Fmi = sE ? 0.f : sFmi;
    };

    for (int pc = 0; pc < NPULSES; pc += CHUNK) {
        // --- compute + stage CHUNK pulses into wave-private LDS ---
        #pragma unroll
        for (int cp = 0; cp < CHUNK; ++cp) {
            step(fa_arr[pc + cp], ph_arr[pc + cp]);
            if (valid) {
                float* dst = ldsw + (cp * EPW + g) * RECF + s * 10;
                ((float2*)dst)[0] = make_float2(Fpr, Fpi);
                ((float2*)dst)[1] = make_float2(Fmr, Fmi);
                dst[4] = Zf;
                dst[9] = Zb;
            }
        }
        // wave-local write->read ordering (DS in-order per wave; belt+braces)
        asm volatile("s_waitcnt lgkmcnt(0)" ::: "memory");

        // --- burst copy: CHUNK x 1680B contiguous dwordx4 streams ---
        #pragma unroll
        for (int cp = 0; cp < CHUNK; ++cp) {
            const v4f* Ls = (const v4f*)(ldsw + cp * EPW * RECF);
            v4f* og = (v4f*)(outw + (size_t)(pc + cp) * pstride);
            #pragma unroll
            for (int i = 0; i < 2; ++i) {
                int idx = lane + i * 64;
                if (idx < (EPW * RECF) / 4)   // 105 float4 per pulse
                    og[idx] = Ls[idx];
            }
        }
        // Reuse safety: each burst store's operand forces lgkmcnt on its
        // ds_read before issue, so all reads of this chunk complete before
        // the next chunk's ds_writes (program order, in-order DS pipe).
    }
}

extern "C" void kernel_launch(void* const* d_in, const int* in_sizes, int n_in,
                              void* d_out, int out_size, void* d_ws, size_t ws_size,
                              hipStream_t stream) {
    const float* fa  = (const float*)d_in[0];
    const float* ph  = (const float*)d_in[1];
    const float* T1f = (const float*)d_in[2];
    const float* T2f = (const float*)d_in[3];
    const float* T1b = (const float*)d_in[4];
    const float* T2b = (const float*)d_in[5];
    const float* kf  = (const float*)d_in[6];
    const float* kb  = (const float*)d_in[7];
    const float* B0  = (const float*)d_in[8];
    const float* B1  = (const float*)d_in[9];
    const float* wf  = (const float*)d_in[10];
    const float* wb  = (const float*)d_in[11];
    const int*   TR  = (const int*)d_in[12];
    float* out = (float*)d_out;

    const int blocks = BATCH / EPB;   // 512 exactly: 2 blocks/CU, no tail
    epg_mt_kernel<<<blocks, WPB * 64, 0, stream>>>(fa, ph, T1f, T2f, T1b, T2b,
                                                   kf, kb, B0, B1, wf, wb, TR, out);
}